// Round 14
// baseline (482.027 us; speedup 1.0000x reference)
//
#include <hip/hip_runtime.h>
#include <cstdint>
#include <cstddef>

#define Tn 1024
#define Bn 64
#define Cn 8
#define Nn 64
#define LDP 65             /* padded row stride for trans_lds */
#define TBC 512            /* tags stride per t */
#define ES 32768           /* emissions stride per t (B*C*N) */
#define GS ((size_t)4 * ES)  /* group stride: 4 t-slices */
#define LN2F 0.69314718056f

typedef float f32x2 __attribute__((ext_vector_type(2)));

// ---- wave64 reductions via DPP ----
__device__ __forceinline__ float wred_max(float x) {
  int v;
#define STEP(ctrl) \
  v = __builtin_amdgcn_update_dpp((int)0xff800000, __float_as_int(x), ctrl, 0xf, 0xf, false); \
  x = fmaxf(x, __int_as_float(v));
  STEP(0x111) STEP(0x112) STEP(0x114) STEP(0x118) STEP(0x142) STEP(0x143)
#undef STEP
  return __int_as_float(__builtin_amdgcn_readlane(__float_as_int(x), 63));
}

__device__ __forceinline__ float wred_sum(float x) {
  int v;
#define STEP(ctrl) \
  v = __builtin_amdgcn_update_dpp(0, __float_as_int(x), ctrl, 0xf, 0xf, false); \
  x = x + __int_as_float(v);
  STEP(0x111) STEP(0x112) STEP(0x114) STEP(0x118) STEP(0x142) STEP(0x143)
#undef STEP
  return __int_as_float(__builtin_amdgcn_readlane(__float_as_int(x), 63));
}

__device__ __forceinline__ float lane0(float x) {
  return __int_as_float(__builtin_amdgcn_readlane(__float_as_int(x), 0));
}

// ---- cross-lane swap-combine primitives (reduce-scatter stages) ----
// comb32(a,b): after v_permlane32_swap on each 32b component, the two results
// at every lane are {my value, partner(lane^32)'s value} of ONE of the sets
// (which set lands on which half is probed at init and compensated in the
// P-column mapping). Sum = set-reduced over the 32-distance.
__device__ __forceinline__ f32x2 comb32(f32x2 a, f32x2 b) {
  int ax = __float_as_int(a.x), bx = __float_as_int(b.x);
  int ay = __float_as_int(a.y), by = __float_as_int(b.y);
  asm("v_permlane32_swap_b32 %0, %1" : "+v"(ax), "+v"(bx));
  asm("v_permlane32_swap_b32 %0, %1" : "+v"(ay), "+v"(by));
  f32x2 r;
  r.x = __int_as_float(ax) + __int_as_float(bx);
  r.y = __int_as_float(ay) + __int_as_float(by);
  return r;
}

__device__ __forceinline__ f32x2 comb16(f32x2 a, f32x2 b) {
  int ax = __float_as_int(a.x), bx = __float_as_int(b.x);
  int ay = __float_as_int(a.y), by = __float_as_int(b.y);
  asm("v_permlane16_swap_b32 %0, %1" : "+v"(ax), "+v"(bx));
  asm("v_permlane16_swap_b32 %0, %1" : "+v"(ay), "+v"(by));
  f32x2 r;
  r.x = __int_as_float(ax) + __int_as_float(bx);
  r.y = __int_as_float(ay) + __int_as_float(by);
  return r;
}

template<int CTRL>
__device__ __forceinline__ f32x2 dpp2(f32x2 x) {
  f32x2 r;
  r.x = __int_as_float(__builtin_amdgcn_update_dpp(0, __float_as_int(x.x), CTRL, 0xf, 0xf, false));
  r.y = __int_as_float(__builtin_amdgcn_update_dpp(0, __float_as_int(x.y), CTRL, 0xf, 0xf, false));
  return r;
}

// ---- reduce-scatter tree: p[k] = lane's partial products for columns
// {c(k), c(k)+1}; returns s_lane = sum over all 64 lanes' contributions to
// column `lane`. Pure VALU: permlane swaps + DPP mirror/quad stages.
__device__ __forceinline__ float tree64(const f32x2 (&p)[32], int lane) {
  f32x2 q[16];
#pragma unroll
  for (int k = 0; k < 16; ++k) q[k] = comb32(p[k], p[k + 16]);     // 64 -> 32-groups
  f32x2 h[8];
#pragma unroll
  for (int k = 0; k < 8; ++k) h[k] = comb16(q[k], q[k + 8]);       // 32 -> 16-groups
  const bool lo8 = ((lane & 15) < 8);                              // 16 -> 8 (row_mirror)
  f32x2 e[4];
#pragma unroll
  for (int k = 0; k < 4; ++k) {
    f32x2 E = h[k] + dpp2<0x140>(h[k]);
    f32x2 F = h[k + 4] + dpp2<0x140>(h[k + 4]);
    e[k].x = lo8 ? E.x : F.x;  e[k].y = lo8 ? E.y : F.y;
  }
  const bool lo4 = ((lane & 7) < 4);                               // 8 -> 4 (row_half_mirror)
  f32x2 f2[2];
#pragma unroll
  for (int k = 0; k < 2; ++k) {
    f32x2 E = e[k] + dpp2<0x141>(e[k]);
    f32x2 F = e[k + 2] + dpp2<0x141>(e[k + 2]);
    f2[k].x = lo4 ? E.x : F.x;  f2[k].y = lo4 ? E.y : F.y;
  }
  const bool lo2 = ((lane & 3) < 2);                               // 4 -> 2 (quad xor2)
  f32x2 E = f2[0] + dpp2<0x4E>(f2[0]);
  f32x2 F = f2[1] + dpp2<0x4E>(f2[1]);
  f32x2 g;
  g.x = lo2 ? E.x : F.x;  g.y = lo2 ? E.y : F.y;
  f32x2 s2 = g + dpp2<0xB1>(g);                                    // 2 -> 1 (quad xor1)
  return (lane & 1) ? s2.y : s2.x;
}

// Linear-space steps via outer product + tree (no LDS/SGPR on the chain).
#define FSTEP_LIN(u, wv) do {                                  \
    f32x2 u2_; u2_.x = (u); u2_.y = (u);                       \
    f32x2 p_[32];                                              \
    _Pragma("unroll")                                          \
    for (int kk_ = 0; kk_ < 32; ++kk_) p_[kk_] = u2_ * P2[kk_];\
    (u) = tree64(p_, lane) * (wv);                             \
  } while (0)

#define BSTEP_LIN(v, wv) do {                                  \
    float vw_ = (v) * (wv);                                    \
    f32x2 u2_; u2_.x = vw_; u2_.y = vw_;                       \
    f32x2 p_[32];                                              \
    _Pragma("unroll")                                          \
    for (int kk_ = 0; kk_ < 32; ++kk_) p_[kk_] = u2_ * P2[kk_];\
    (v) = tree64(p_, lane);                                    \
  } while (0)

// r8-verified per-group rescale (lane0 exponent, exact 2^-k, integer Lk).
#define RESCALE0(u, Lk) do {                        \
    int ke_ = (__builtin_amdgcn_readlane(__float_as_int(u), 0) >> 23) & 255; \
    (Lk) += ke_ - 127;                              \
    (u) *= __int_as_float((254 - ke_) << 23);       \
  } while (0)

// Exact max-based rescale (epilogue only).
#define RESCALE(u, Lk) do {                         \
    float mx_ = wred_max(u);                        \
    int ke_ = (__float_as_int(mx_) >> 23) & 255;    \
    (Lk) += ke_ - 127;                              \
    (u) *= __int_as_float((254 - ke_) << 23);       \
  } while (0)

__global__ __launch_bounds__(128, 1)
void crf_fwd(const float* __restrict__ em, const int* __restrict__ tags,
             const int* __restrict__ lengths, const float* __restrict__ trans,
             const float* __restrict__ head, const float* __restrict__ tail,
             float* __restrict__ out) {
  __shared__ float trans_lds[Nn * LDP];               // 16.6 KB
  __shared__ __align__(16) float ring[2][4 * 4 * Nn]; // per-wave 4-group em ring
  __shared__ float blds[Nn];
  __shared__ float scw[2];
  __shared__ float sc_ht;
  __shared__ float lbshift;

  const int bid = blockIdx.x;                         // 512 = B*C chains
  const int b = bid >> 3, c = bid & 7;
  const int tid = threadIdx.x;
  const int w = __builtin_amdgcn_readfirstlane(tid >> 6);  // 0 = fwd, 1 = bwd
  const int lane = tid & 63;
  const int bc = b * Cn + c;
  const int len = lengths[b];                         // [512, 1024]
  const int m = len >> 1;

  // ---- probe permlane swap direction once (wave-uniform flips) ----
  int flip32, flip16;
  {
    int pa = lane, pb = lane + 1024;
    asm volatile("v_permlane32_swap_b32 %0, %1" : "+v"(pa), "+v"(pb));
    int v0 = __builtin_amdgcn_readfirstlane(pa + pb);   // 32 (first-op set low) or 2080
    flip32 = (v0 == 32) ? 0 : 32;
    int pc = lane, pd = lane + 2048;
    asm volatile("v_permlane16_swap_b32 %0, %1" : "+v"(pc), "+v"(pd));
    int v1 = __builtin_amdgcn_readfirstlane(pc + pd);   // 16 (first-op set even rows) or 4112
    flip16 = (v1 == 16) ? 0 : 16;
  }

  // ---- stage transitions[c] into LDS, stride 65 ----
  const float* tc = trans + c * Nn * Nn;
  for (int k = tid; k < Nn * Nn; k += 128) trans_lds[(k >> 6) * LDP + (k & 63)] = tc[k];
  __syncthreads();

  // ---- log_scores phase ----
  float sc = 0.f;
#pragma unroll
  for (int it = 0; it < 8; ++it) {
    int t = it * 128 + tid;
    if (t < len) {
      int tagc = tags[t * TBC + bc];
      sc += em[(size_t)t * ES + (size_t)bc * Nn + tagc];
      if (t >= 1) {
        int tagp = tags[(t - 1) * TBC + bc];
        sc += trans_lds[tagp * LDP + tagc];
      }
    }
  }
  sc = wred_sum(sc);
  if (lane == 0) scw[w] = sc;
  if (tid == 0) {
    int tag0 = tags[bc];
    int tagl = tags[(len - 1) * TBC + bc];
    sc_ht = head[c * Nn + tag0] + tail[c * Nn + tagl];
  }

  // ---- per-wave P fragment for the OUTER formulation ----
  // fwd (sources = rows, lane holds ROW `lane`): P2[k] = e^{T[lane][c..c+1]}
  // bwd (sources = cols, lane holds COLUMN `lane`): P2[k] = e^{T[c..c+1][lane]}
  // Column mapping per tree slot k, with probe flips folded in:
  //   c(k) = 2*(k&7) + ((k>>3 & 1)*16 ^ flip16) + ((k>>4 & 1)*32 ^ flip32)
  f32x2 P2[32];
#pragma unroll
  for (int k = 0; k < 32; ++k) {
    int cc = 2 * (k & 7) + ((((k >> 3) & 1) * 16) ^ flip16) + ((((k >> 4) & 1) * 32) ^ flip32);
    f32x2 p;
    if (w == 0) {
      p.x = __expf(trans_lds[lane * LDP + cc]);
      p.y = __expf(trans_lds[lane * LDP + cc + 1]);
    } else {
      p.x = __expf(trans_lds[cc * LDP + lane]);
      p.y = __expf(trans_lds[(cc + 1) * LDP + lane]);
    }
    P2[k] = p;
  }

  float* myring = ring[w];
  float state = 0.f;
  float shift0 = 0.f;
  int   Lk = 0;

  if (w == 0) {
    // ======== forward: steps i=0..m-1 consume em slice t=1+i ========
    float al0 = head[c * Nn + lane] + em[(size_t)bc * Nn + lane];
    shift0 = lane0(al0);
    float u = __expf(al0 - shift0);
    const float* g4 = em + (size_t)(1 + (lane >> 4)) * ES + (size_t)bc * Nn + ((lane & 15) << 2);
    const int ns = m, G = ns >> 2, r = ns & 3;

    float4 v0 = *(const float4*)(g4);
    float4 v1 = *(const float4*)(g4 + GS);
    float4 Ast = *(const float4*)(g4 + 2 * GS);
    *(float4*)&myring[0 * 256 + lane * 4] = v0;
    *(float4*)&myring[1 * 256 + lane * 4] = v1;
    float c0 = __expf(myring[0 * 256 +   0 + lane]), c1 = __expf(myring[0 * 256 +  64 + lane]),
          c2 = __expf(myring[0 * 256 + 128 + lane]), c3 = __expf(myring[0 * 256 + 192 + lane]);

    for (int g = 0; g < G; ++g) {
      *(float4*)&myring[((g + 2) & 3) * 256 + lane * 4] = Ast;   // commit group g+2
      Ast = *(const float4*)(g4 + (size_t)(g + 3) * GS);         // fetch group g+3 (slice <= m+12 < 1024)
      const int s1 = ((g + 1) & 3) * 256;
      float n0 = myring[s1 + lane],       n1 = myring[s1 + 64 + lane],
            n2 = myring[s1 + 128 + lane], n3 = myring[s1 + 192 + lane];
      FSTEP_LIN(u, c0); FSTEP_LIN(u, c1); FSTEP_LIN(u, c2); FSTEP_LIN(u, c3);
      RESCALE0(u, Lk);
      c0 = __expf(n0); c1 = __expf(n1); c2 = __expf(n2); c3 = __expf(n3);
    }
    if (r > 0) { FSTEP_LIN(u, c0); }
    if (r > 1) { FSTEP_LIN(u, c1); }
    if (r > 2) { FSTEP_LIN(u, c2); }
    RESCALE(u, Lk);                                   // exact normalize at meet point
    state = u;                                        // u_m = e^{alpha_m - A0 - Lk*ln2}
  } else {
    // ======== backward: steps k=0..nb-1 consume em slice len-1-k ========
    float tl = tail[c * Nn + lane];
    shift0 = lane0(tl);
    float v = __expf(tl - shift0);
    const int ns = len - 1 - m, G = ns >> 2, r = ns & 3;
    const float* g4 = em + (size_t)(len - 1 - (lane >> 4)) * ES + (size_t)bc * Nn + ((lane & 15) << 2);

    float4 v0 = *(const float4*)(g4);
    float4 v1 = *(const float4*)(g4 - GS);
    float4 Ast = *(const float4*)(g4 - 2 * GS);
    *(float4*)&myring[0 * 256 + lane * 4] = v0;
    *(float4*)&myring[1 * 256 + lane * 4] = v1;
    float c0 = __expf(myring[0 * 256 +   0 + lane]), c1 = __expf(myring[0 * 256 +  64 + lane]),
          c2 = __expf(myring[0 * 256 + 128 + lane]), c3 = __expf(myring[0 * 256 + 192 + lane]);

    for (int g = 0; g < G; ++g) {
      *(float4*)&myring[((g + 2) & 3) * 256 + lane * 4] = Ast;
      Ast = *(const float4*)(g4 - (size_t)(g + 3) * GS);         // slice >= m-11 >= 0
      const int s1 = ((g + 1) & 3) * 256;
      float n0 = myring[s1 + lane],       n1 = myring[s1 + 64 + lane],
            n2 = myring[s1 + 128 + lane], n3 = myring[s1 + 192 + lane];
      BSTEP_LIN(v, c0); BSTEP_LIN(v, c1); BSTEP_LIN(v, c2); BSTEP_LIN(v, c3);
      RESCALE0(v, Lk);
      c0 = __expf(n0); c1 = __expf(n1); c2 = __expf(n2); c3 = __expf(n3);
    }
    if (r > 0) { BSTEP_LIN(v, c0); }
    if (r > 1) { BSTEP_LIN(v, c1); }
    if (r > 2) { BSTEP_LIN(v, c2); }
    RESCALE(v, Lk);                                   // exact normalize at meet point
    blds[lane] = v;                                   // v_m = e^{beta_m - B0 - Lk*ln2}
    if (lane == 0) lbshift = shift0 + (float)Lk * LN2F;
  }

  __syncthreads();                                    // both waves hit exactly once

  if (w == 0) {
    float p = state * blds[lane];                     // max ~4, positive terms
    float ssum = wred_sum(p);
    if (lane == 0) {
      float logZ = __logf(ssum) + shift0 + (float)Lk * LN2F + lbshift;
      out[bc] = scw[0] + scw[1] + sc_ht - logZ;
    }
  }
}

extern "C" void kernel_launch(void* const* d_in, const int* in_sizes, int n_in,
                              void* d_out, int out_size, void* d_ws, size_t ws_size,
                              hipStream_t stream) {
  const float* em      = (const float*)d_in[0];
  const int*   tags    = (const int*)d_in[1];
  const int*   lengths = (const int*)d_in[2];
  const float* trans   = (const float*)d_in[3];
  const float* head    = (const float*)d_in[4];
  const float* tail    = (const float*)d_in[5];
  float* out = (float*)d_out;
  crf_fwd<<<dim3(Bn * Cn), dim3(128), 0, stream>>>(em, tags, lengths, trans, head, tail, out);
}

// Round 15
// 128.246 us; speedup vs baseline: 3.7586x; 3.7586x over previous
//
#include <hip/hip_runtime.h>
#include <cstdint>
#include <cstddef>

#define Tn 1024
#define Bn 64
#define Cn 8
#define Nn 64
#define LDP 65             /* padded row stride for trans_lds */
#define TBC 512            /* tags stride per t */
#define ES 32768           /* emissions stride per t (B*C*N) */
#define GS ((size_t)4 * ES)  /* group stride: 4 t-slices */
#define LN2F 0.69314718056f

typedef float f32x2 __attribute__((ext_vector_type(2)));
typedef float f32x4 __attribute__((ext_vector_type(4)));

// ---- wave64 reductions via DPP ----
__device__ __forceinline__ float wred_max(float x) {
  int v;
#define STEP(ctrl) \
  v = __builtin_amdgcn_update_dpp((int)0xff800000, __float_as_int(x), ctrl, 0xf, 0xf, false); \
  x = fmaxf(x, __int_as_float(v));
  STEP(0x111) STEP(0x112) STEP(0x114) STEP(0x118) STEP(0x142) STEP(0x143)
#undef STEP
  return __int_as_float(__builtin_amdgcn_readlane(__float_as_int(x), 63));
}

__device__ __forceinline__ float wred_sum(float x) {
  int v;
#define STEP(ctrl) \
  v = __builtin_amdgcn_update_dpp(0, __float_as_int(x), ctrl, 0xf, 0xf, false); \
  x = x + __int_as_float(v);
  STEP(0x111) STEP(0x112) STEP(0x114) STEP(0x118) STEP(0x142) STEP(0x143)
#undef STEP
  return __int_as_float(__builtin_amdgcn_readlane(__float_as_int(x), 63));
}

__device__ __forceinline__ float lane0(float x) {
  return __int_as_float(__builtin_amdgcn_readlane(__float_as_int(x), 0));
}

// ---- FMA quads (r8-verified math): even quads -> (A0,A1), odd -> (A2,A3) ----
#define MQE(t_, k) \
  A0_ += __builtin_shufflevector(t_, t_, 0, 1) * P2[2*(k)]; \
  A1_ += __builtin_shufflevector(t_, t_, 2, 3) * P2[2*(k)+1];
#define MQO(t_, k) \
  A2_ += __builtin_shufflevector(t_, t_, 0, 1) * P2[2*(k)]; \
  A3_ += __builtin_shufflevector(t_, t_, 2, 3) * P2[2*(k)+1];

// ---- asm-scheduled uniform-broadcast 64x64 matvec ----
// Same-wave DS ops execute IN ORDER through the LDS pipe, so the 16 broadcast
// reads issued right after the ds_write return the new data with no
// intermediate waitcnt. Counted lgkmcnt overlaps the FMA batches under the
// later read returns (T4 pattern). sched_barrier(0) after each wait stops the
// backend hoisting register-only FMAs above it (rule #18).
#define MVBODY(UIN) \
  f32x4 q0_,q1_,q2_,q3_,q4_,q5_,q6_,q7_,q8_,q9_,q10_,q11_,q12_,q13_,q14_,q15_; \
  asm volatile("ds_write_b32 %0, %1" :: "v"(ewa), "v"(UIN)); \
  asm volatile("ds_read_b128 %0, %1 offset:0"   : "=v"(q0_)  : "v"(erb)); \
  asm volatile("ds_read_b128 %0, %1 offset:16"  : "=v"(q1_)  : "v"(erb)); \
  asm volatile("ds_read_b128 %0, %1 offset:32"  : "=v"(q2_)  : "v"(erb)); \
  asm volatile("ds_read_b128 %0, %1 offset:48"  : "=v"(q3_)  : "v"(erb)); \
  asm volatile("ds_read_b128 %0, %1 offset:64"  : "=v"(q4_)  : "v"(erb)); \
  asm volatile("ds_read_b128 %0, %1 offset:80"  : "=v"(q5_)  : "v"(erb)); \
  asm volatile("ds_read_b128 %0, %1 offset:96"  : "=v"(q6_)  : "v"(erb)); \
  asm volatile("ds_read_b128 %0, %1 offset:112" : "=v"(q7_)  : "v"(erb)); \
  asm volatile("ds_read_b128 %0, %1 offset:128" : "=v"(q8_)  : "v"(erb)); \
  asm volatile("ds_read_b128 %0, %1 offset:144" : "=v"(q9_)  : "v"(erb)); \
  asm volatile("ds_read_b128 %0, %1 offset:160" : "=v"(q10_) : "v"(erb)); \
  asm volatile("ds_read_b128 %0, %1 offset:176" : "=v"(q11_) : "v"(erb)); \
  asm volatile("ds_read_b128 %0, %1 offset:192" : "=v"(q12_) : "v"(erb)); \
  asm volatile("ds_read_b128 %0, %1 offset:208" : "=v"(q13_) : "v"(erb)); \
  asm volatile("ds_read_b128 %0, %1 offset:224" : "=v"(q14_) : "v"(erb)); \
  asm volatile("ds_read_b128 %0, %1 offset:240" : "=v"(q15_) : "v"(erb)); \
  f32x2 A0_ = {0.f, 0.f}, A1_ = A0_, A2_ = A0_, A3_ = A0_; \
  asm volatile("s_waitcnt lgkmcnt(12)" ::: "memory"); \
  __builtin_amdgcn_sched_barrier(0); \
  MQE(q0_,0) MQO(q1_,1) MQE(q2_,2) MQO(q3_,3) \
  asm volatile("s_waitcnt lgkmcnt(8)" ::: "memory"); \
  __builtin_amdgcn_sched_barrier(0); \
  MQE(q4_,4) MQO(q5_,5) MQE(q6_,6) MQO(q7_,7) \
  asm volatile("s_waitcnt lgkmcnt(4)" ::: "memory"); \
  __builtin_amdgcn_sched_barrier(0); \
  MQE(q8_,8) MQO(q9_,9) MQE(q10_,10) MQO(q11_,11) \
  asm volatile("s_waitcnt lgkmcnt(0)" ::: "memory"); \
  __builtin_amdgcn_sched_barrier(0); \
  MQE(q12_,12) MQO(q13_,13) MQE(q14_,14) MQO(q15_,15) \
  f32x2 S_ = (A0_ + A1_) + (A2_ + A3_); \
  float s_ = S_.x + S_.y;

// Linear-space forward step: u'_j = w_j * sum_i P_ij u_i
#define FSTEP_LIN(u, wv) do { MVBODY(u); (u) = s_ * (wv); } while (0)
// Linear-space backward step: v_i = sum_j P_ij (w_j v'_j)
#define BSTEP_LIN(v, wv) do { float vw_ = (v) * (wv); MVBODY(vw_); (v) = s_; } while (0)

// r8-verified per-group rescale (lane0 exponent, exact 2^-k, integer Lk).
#define RESCALE0(u, Lk) do {                        \
    int ke_ = (__builtin_amdgcn_readlane(__float_as_int(u), 0) >> 23) & 255; \
    (Lk) += ke_ - 127;                              \
    (u) *= __int_as_float((254 - ke_) << 23);       \
  } while (0)

// Exact max-based rescale (epilogue only).
#define RESCALE(u, Lk) do {                         \
    float mx_ = wred_max(u);                        \
    int ke_ = (__float_as_int(mx_) >> 23) & 255;    \
    (Lk) += ke_ - 127;                              \
    (u) *= __int_as_float((254 - ke_) << 23);       \
  } while (0)

__global__ __launch_bounds__(128, 1)
void crf_fwd(const float* __restrict__ em, const int* __restrict__ tags,
             const int* __restrict__ lengths, const float* __restrict__ trans,
             const float* __restrict__ head, const float* __restrict__ tail,
             float* __restrict__ out) {
  __shared__ float trans_lds[Nn * LDP];               // 16.6 KB
  __shared__ __align__(16) float ring[2][4 * 4 * Nn]; // per-wave 4-group em ring
  __shared__ __align__(16) float ebuf[2][Nn];         // per-wave broadcast buffer
  __shared__ float blds[Nn];
  __shared__ float scw[2];
  __shared__ float sc_ht;
  __shared__ float lbshift;

  const int bid = blockIdx.x;                         // 512 = B*C chains
  const int b = bid >> 3, c = bid & 7;
  const int tid = threadIdx.x;
  const int w = __builtin_amdgcn_readfirstlane(tid >> 6);  // 0 = fwd, 1 = bwd
  const int lane = tid & 63;
  const int bc = b * Cn + c;
  const int len = lengths[b];                         // [512, 1024]
  const int m = len >> 1;

  // ---- stage transitions[c] into LDS, stride 65 ----
  const float* tc = trans + c * Nn * Nn;
  for (int k = tid; k < Nn * Nn; k += 128) trans_lds[(k >> 6) * LDP + (k & 63)] = tc[k];
  __syncthreads();

  // ---- log_scores phase ----
  float sc = 0.f;
#pragma unroll
  for (int it = 0; it < 8; ++it) {
    int t = it * 128 + tid;
    if (t < len) {
      int tagc = tags[t * TBC + bc];
      sc += em[(size_t)t * ES + (size_t)bc * Nn + tagc];
      if (t >= 1) {
        int tagp = tags[(t - 1) * TBC + bc];
        sc += trans_lds[tagp * LDP + tagc];
      }
    }
  }
  sc = wred_sum(sc);
  if (lane == 0) scw[w] = sc;
  if (tid == 0) {
    int tag0 = tags[bc];
    int tagl = tags[(len - 1) * TBC + bc];
    sc_ht = head[c * Nn + tag0] + tail[c * Nn + tagl];
  }

  // ---- per-wave P2 fragment (f32x2 pairs, VGPR-resident) ----
  // fwd: P[i] = exp(trans[i][lane]);  bwd: P[j] = exp(trans[lane][j])
  f32x2 P2[32];
  if (w == 0) {
#pragma unroll
    for (int k = 0; k < 32; ++k) {
      f32x2 p; p.x = __expf(trans_lds[(2 * k) * LDP + lane]);
      p.y = __expf(trans_lds[(2 * k + 1) * LDP + lane]);
      P2[k] = p;
    }
  } else {
#pragma unroll
    for (int k = 0; k < 32; ++k) {
      f32x2 p; p.x = __expf(trans_lds[lane * LDP + 2 * k]);
      p.y = __expf(trans_lds[lane * LDP + 2 * k + 1]);
      P2[k] = p;
    }
  }

  float* myring = ring[w];
  float* ew = ebuf[w];
  // LDS byte addresses for the asm matvec (generic->LDS low-32 truncation idiom)
  const uint32_t erb = (uint32_t)(uintptr_t)&ew[0];
  const uint32_t ewa = erb + 4u * (uint32_t)lane;
  float state = 0.f;
  float shift0 = 0.f;
  int   Lk = 0;

  if (w == 0) {
    // ======== forward: steps i=0..m-1 consume em slice t=1+i ========
    float al0 = head[c * Nn + lane] + em[(size_t)bc * Nn + lane];
    shift0 = lane0(al0);
    float u = __expf(al0 - shift0);
    const float* g4 = em + (size_t)(1 + (lane >> 4)) * ES + (size_t)bc * Nn + ((lane & 15) << 2);
    const int ns = m, G = ns >> 2, r = ns & 3;

    float4 v0 = *(const float4*)(g4);
    float4 v1 = *(const float4*)(g4 + GS);
    float4 Ast = *(const float4*)(g4 + 2 * GS);
    *(float4*)&myring[0 * 256 + lane * 4] = v0;
    *(float4*)&myring[1 * 256 + lane * 4] = v1;
    float c0 = __expf(myring[0 * 256 +   0 + lane]), c1 = __expf(myring[0 * 256 +  64 + lane]),
          c2 = __expf(myring[0 * 256 + 128 + lane]), c3 = __expf(myring[0 * 256 + 192 + lane]);

    for (int g = 0; g < G; ++g) {
      *(float4*)&myring[((g + 2) & 3) * 256 + lane * 4] = Ast;   // commit group g+2
      Ast = *(const float4*)(g4 + (size_t)(g + 3) * GS);         // fetch group g+3 (slice <= m+12 < 1024)
      const int s1 = ((g + 1) & 3) * 256;
      float n0 = myring[s1 + lane],       n1 = myring[s1 + 64 + lane],
            n2 = myring[s1 + 128 + lane], n3 = myring[s1 + 192 + lane];
      FSTEP_LIN(u, c0); FSTEP_LIN(u, c1); FSTEP_LIN(u, c2); FSTEP_LIN(u, c3);
      RESCALE0(u, Lk);
      c0 = __expf(n0); c1 = __expf(n1); c2 = __expf(n2); c3 = __expf(n3);
    }
    if (r > 0) { FSTEP_LIN(u, c0); }
    if (r > 1) { FSTEP_LIN(u, c1); }
    if (r > 2) { FSTEP_LIN(u, c2); }
    RESCALE(u, Lk);                                   // exact normalize at meet point
    state = u;                                        // u_m = e^{alpha_m - A0 - Lk*ln2}
  } else {
    // ======== backward: steps k=0..nb-1 consume em slice len-1-k ========
    float tl = tail[c * Nn + lane];
    shift0 = lane0(tl);
    float v = __expf(tl - shift0);
    const int ns = len - 1 - m, G = ns >> 2, r = ns & 3;
    const float* g4 = em + (size_t)(len - 1 - (lane >> 4)) * ES + (size_t)bc * Nn + ((lane & 15) << 2);

    float4 v0 = *(const float4*)(g4);
    float4 v1 = *(const float4*)(g4 - GS);
    float4 Ast = *(const float4*)(g4 - 2 * GS);
    *(float4*)&myring[0 * 256 + lane * 4] = v0;
    *(float4*)&myring[1 * 256 + lane * 4] = v1;
    float c0 = __expf(myring[0 * 256 +   0 + lane]), c1 = __expf(myring[0 * 256 +  64 + lane]),
          c2 = __expf(myring[0 * 256 + 128 + lane]), c3 = __expf(myring[0 * 256 + 192 + lane]);

    for (int g = 0; g < G; ++g) {
      *(float4*)&myring[((g + 2) & 3) * 256 + lane * 4] = Ast;
      Ast = *(const float4*)(g4 - (size_t)(g + 3) * GS);         // slice >= m-11 >= 0
      const int s1 = ((g + 1) & 3) * 256;
      float n0 = myring[s1 + lane],       n1 = myring[s1 + 64 + lane],
            n2 = myring[s1 + 128 + lane], n3 = myring[s1 + 192 + lane];
      BSTEP_LIN(v, c0); BSTEP_LIN(v, c1); BSTEP_LIN(v, c2); BSTEP_LIN(v, c3);
      RESCALE0(v, Lk);
      c0 = __expf(n0); c1 = __expf(n1); c2 = __expf(n2); c3 = __expf(n3);
    }
    if (r > 0) { BSTEP_LIN(v, c0); }
    if (r > 1) { BSTEP_LIN(v, c1); }
    if (r > 2) { BSTEP_LIN(v, c2); }
    RESCALE(v, Lk);                                   // exact normalize at meet point
    blds[lane] = v;                                   // v_m = e^{beta_m - B0 - Lk*ln2}
    if (lane == 0) lbshift = shift0 + (float)Lk * LN2F;
  }

  __syncthreads();                                    // both waves hit exactly once

  if (w == 0) {
    float p = state * blds[lane];                     // max ~4, positive terms
    float ssum = wred_sum(p);
    if (lane == 0) {
      float logZ = __logf(ssum) + shift0 + (float)Lk * LN2F + lbshift;
      out[bc] = scw[0] + scw[1] + sc_ht - logZ;
    }
  }
}

extern "C" void kernel_launch(void* const* d_in, const int* in_sizes, int n_in,
                              void* d_out, int out_size, void* d_ws, size_t ws_size,
                              hipStream_t stream) {
  const float* em      = (const float*)d_in[0];
  const int*   tags    = (const int*)d_in[1];
  const int*   lengths = (const int*)d_in[2];
  const float* trans   = (const float*)d_in[3];
  const float* head    = (const float*)d_in[4];
  const float* tail    = (const float*)d_in[5];
  float* out = (float*)d_out;
  crf_fwd<<<dim3(Bn * Cn), dim3(128), 0, stream>>>(em, tags, lengths, trans, head, tail, out);
}